// Round 3
// baseline (431.907 us; speedup 1.0000x reference)
//
#include <hip/hip_runtime.h>

typedef __bf16 bf16;
typedef bf16 bf16x8 __attribute__((ext_vector_type(8)));
typedef float floatx4 __attribute__((ext_vector_type(4)));

#define AS1 __attribute__((address_space(1)))
#define AS3 __attribute__((address_space(3)))

// ---------------------------------------------------------------------------
// Core tile machinery: 128x128 block, 4 waves (2x2 of 64x64), BK=64,
// 16x16x32 bf16 MFMA. Both operands stored [row][k] (k-contiguous).
// Staging: global_load_lds width=16, lane-contiguous LDS, XOR swizzle applied
// to the GLOBAL column so ds_read_b128 fragment loads are conflict-free.
// ---------------------------------------------------------------------------
__device__ __forceinline__ void stage_tile(const bf16* g, int ld, bf16* lds, int tid) {
#pragma unroll
    for (int it = 0; it < 4; ++it) {
        int q    = it * 256 + tid;        // 0..1023, 8 bf16 per q
        int row  = q >> 3;
        int col8 = (q & 7) ^ (row & 7);   // swizzle on global side
        __builtin_amdgcn_global_load_lds(
            (const AS1 void*)(g + (size_t)row * ld + col8 * 8),
            (AS3 void*)(lds + q * 8), 16, 0, 0);
    }
}

__device__ __forceinline__ void mfma_block(const bf16* lA, const bf16* lB,
                                           floatx4 acc[4][4], int lane, int wm, int wn) {
    const int lrow = lane & 15;
    const int lk   = lane >> 4;
#pragma unroll
    for (int s = 0; s < 2; ++s) {   // two K=32 steps per BK=64
        bf16x8 af[4], bfr[4];
        const int c8 = s * 4 + lk;
#pragma unroll
        for (int mi = 0; mi < 4; ++mi) {
            int r = wm * 64 + mi * 16 + lrow;
            af[mi] = *(const bf16x8*)(lA + r * 64 + ((c8 ^ (r & 7)) << 3));
        }
#pragma unroll
        for (int ni = 0; ni < 4; ++ni) {
            int r = wn * 64 + ni * 16 + lrow;
            bfr[ni] = *(const bf16x8*)(lB + r * 64 + ((c8 ^ (r & 7)) << 3));
        }
#pragma unroll
        for (int mi = 0; mi < 4; ++mi)
#pragma unroll
            for (int ni = 0; ni < 4; ++ni)
                acc[mi][ni] = __builtin_amdgcn_mfma_f32_16x16x32_bf16(
                    af[mi], bfr[ni], acc[mi][ni], 0, 0, 0);
    }
}

// ---------------------------------------------------------------------------
// GEMM1: YT[kv*512+o][t] = sum_d WbT[kv*512+o][d] * xb[t][d]
// ---------------------------------------------------------------------------
__global__ __launch_bounds__(256) void yt_gemm(const bf16* __restrict__ WbT,
                                               const bf16* __restrict__ xb,
                                               bf16* __restrict__ YT) {
    __shared__ bf16 lA[128 * 64], lB[128 * 64];
    const int tid = threadIdx.x;
    const int lane = tid & 63, wave = tid >> 6, wm = wave & 1, wn = wave >> 1;
    const int bm = blockIdx.x, bn = blockIdx.y;
    const bf16* Ab = WbT + (size_t)bm * 128 * 512;
    const bf16* Bb = xb + (size_t)bn * 128 * 512;

    floatx4 acc[4][4];
    floatx4 zero = {0.f, 0.f, 0.f, 0.f};
#pragma unroll
    for (int mi = 0; mi < 4; ++mi)
#pragma unroll
        for (int ni = 0; ni < 4; ++ni) acc[mi][ni] = zero;

    for (int kk = 0; kk < 512; kk += 64) {
        stage_tile(Ab + kk, 512, lA, tid);
        stage_tile(Bb + kk, 512, lB, tid);
        __syncthreads();
        mfma_block(lA, lB, acc, lane, wm, wn);
        __syncthreads();
    }
#pragma unroll
    for (int mi = 0; mi < 4; ++mi)
#pragma unroll
        for (int ni = 0; ni < 4; ++ni)
#pragma unroll
            for (int r = 0; r < 4; ++r) {
                int ko = bm * 128 + wm * 64 + mi * 16 + (lane >> 4) * 4 + r;
                int t  = bn * 128 + wn * 64 + ni * 16 + (lane & 15);
                YT[(size_t)ko * 2048 + t] = (bf16)acc[mi][ni][r];
            }
}

// ---------------------------------------------------------------------------
// conv GEMM, kv-split by 4: one block per (p=(a,c), n, s). Grid 2176.
// 2176 tasks / 768 resident (3 blk/CU) = 2.83 -> 3 rounds, 94% fill.
// K = 12 kv slices x 128. Epilogue: atomicAdd straight into out (pre-zeroed).
// ---------------------------------------------------------------------------
__global__ __launch_bounds__(256) void conv_gemm(const bf16* __restrict__ Tb,
                                                 const bf16* __restrict__ YT,
                                                 float* __restrict__ out) {
    __shared__ bf16 lA[128 * 64], lB[128 * 64];
    const int tid = threadIdx.x;
    const int lane = tid & 63, wave = tid >> 6, wm = wave & 1, wn = wave >> 1;
    const int bid = blockIdx.x;
    const int s  = bid & 3;
    const int n  = (bid >> 2) & 3;
    const int p  = bid >> 4;
    int a = 0;
    while ((a + 1) * (a + 2) / 2 <= p) ++a;   // uniform scalar loop, <=16 iters
    const int c = p - a * (a + 1) / 2;
    const int m = a - c;

    floatx4 acc[4][4];
    floatx4 zero = {0.f, 0.f, 0.f, 0.f};
#pragma unroll
    for (int mi = 0; mi < 4; ++mi)
#pragma unroll
        for (int ni = 0; ni < 4; ++ni) acc[mi][ni] = zero;

    const bf16* Ab0 = Tb + (size_t)m * 16384;
    const bf16* Bb0 = YT + (size_t)n * 128 * 2048 + c * 128;
    for (int kv = s * 12; kv < s * 12 + 12; ++kv) {
        const bf16* Ab = Ab0 + (size_t)kv * 16 * 16384;
        const bf16* Bb = Bb0 + (size_t)kv * 1048576;
#pragma unroll
        for (int kk = 0; kk < 128; kk += 64) {
            stage_tile(Ab + kk, 128, lA, tid);
            stage_tile(Bb + kk, 2048, lB, tid);
            __syncthreads();
            mfma_block(lA, lB, acc, lane, wm, wn);
            __syncthreads();
        }
    }
    float* Ob = out + (size_t)(a * 128) * 512 + n * 128;
#pragma unroll
    for (int mi = 0; mi < 4; ++mi)
#pragma unroll
        for (int ni = 0; ni < 4; ++ni)
#pragma unroll
            for (int r = 0; r < 4; ++r) {
                int row = wm * 64 + mi * 16 + (lane >> 4) * 4 + r;  // t-local
                int col = wn * 64 + ni * 16 + (lane & 15);          // o-local
                unsafeAtomicAdd(&Ob[(size_t)row * 512 + col], acc[mi][ni][r]);
            }
}

// ---------------------------------------------------------------------------
// AR GEMM: out[t][o] += sum_{i,d} xar[t][i*512+d] * arWT[o][i*512+d]. K=1536.
// Runs after conv_gemm (stream order) -> plain read-modify-write is safe.
// ---------------------------------------------------------------------------
__global__ __launch_bounds__(256) void ar_gemm(const bf16* __restrict__ xar,
                                               const bf16* __restrict__ arWT,
                                               float* __restrict__ out) {
    __shared__ bf16 lA[128 * 64], lB[128 * 64];
    const int tid = threadIdx.x;
    const int lane = tid & 63, wave = tid >> 6, wm = wave & 1, wn = wave >> 1;
    const int bm = blockIdx.x, bn = blockIdx.y;
    const bf16* Ab = xar + (size_t)bm * 128 * 1536;
    const bf16* Bb = arWT + (size_t)bn * 128 * 1536;

    floatx4 acc[4][4];
    floatx4 zero = {0.f, 0.f, 0.f, 0.f};
#pragma unroll
    for (int mi = 0; mi < 4; ++mi)
#pragma unroll
        for (int ni = 0; ni < 4; ++ni) acc[mi][ni] = zero;

    for (int kk = 0; kk < 1536; kk += 64) {
        stage_tile(Ab + kk, 1536, lA, tid);
        stage_tile(Bb + kk, 1536, lB, tid);
        __syncthreads();
        mfma_block(lA, lB, acc, lane, wm, wn);
        __syncthreads();
    }
#pragma unroll
    for (int mi = 0; mi < 4; ++mi)
#pragma unroll
        for (int ni = 0; ni < 4; ++ni)
#pragma unroll
            for (int r = 0; r < 4; ++r) {
                int t = bm * 128 + wm * 64 + mi * 16 + (lane >> 4) * 4 + r;
                int o = bn * 128 + wn * 64 + ni * 16 + (lane & 15);
                size_t ix = (size_t)t * 512 + o;
                out[ix] = out[ix] + acc[mi][ni][r];
            }
}

// ---------------------------------------------------------------------------
// Fused prep: block ranges dispatch prep_x / prep_wbt / prep_arwt / prep_tb
// ---------------------------------------------------------------------------
__global__ void prep_all(const float* __restrict__ x, const float* __restrict__ phi,
                         const float* __restrict__ M, const float* __restrict__ Mp,
                         const float* __restrict__ Mm, bf16* __restrict__ xb,
                         bf16* __restrict__ xar, bf16* __restrict__ WbT,
                         bf16* __restrict__ arWT, bf16* __restrict__ Tb) {
    __shared__ float smem[64 * 65];
    const int b = blockIdx.x, tid = threadIdx.x;
    if (b < 512) {
        // prep_x, 8 d's per thread: idx8 over 2048*64
        int idx8 = b * 256 + tid;
        int t = idx8 >> 6, d8 = (idx8 & 63) * 8;
        const float* xp = x + (size_t)t * 512 + d8;
        bf16x8 v;
#pragma unroll
        for (int jj = 0; jj < 8; ++jj) v[jj] = (bf16)xp[jj];
        *(bf16x8*)(xb + (size_t)t * 512 + d8) = v;
#pragma unroll
        for (int i = 0; i < 3; ++i) {
            bf16x8 w;
            if (t - i >= 0) {
                const float* xq = xp - (size_t)i * 512;
#pragma unroll
                for (int jj = 0; jj < 8; ++jj) w[jj] = (bf16)xq[jj];
            } else {
#pragma unroll
                for (int jj = 0; jj < 8; ++jj) w[jj] = (bf16)0.f;
            }
            *(bf16x8*)(xar + (size_t)t * 1536 + i * 512 + d8) = w;
        }
    } else if (b < 3584) {
        // prep_wbt: WbT[(kv*512+o)][d] = Mp/Mm[k][d][o] via 64x64 LDS transpose
        int b2 = b - 512;
        int kv = b2 >> 6, rem = b2 & 63;
        int dt = (rem >> 3) * 64, ot = (rem & 7) * 64;
        const float* src = (kv < 24) ? (Mp + (size_t)kv * 262144)
                                     : (Mm + (size_t)(kv - 24) * 262144);
#pragma unroll
        for (int it = 0; it < 16; ++it) {
            int q = it * 256 + tid;
            int r = q >> 6, cc = q & 63;
            smem[r * 65 + cc] = src[(size_t)(dt + r) * 512 + ot + cc];
        }
        __syncthreads();
#pragma unroll
        for (int it = 0; it < 16; ++it) {
            int q = it * 256 + tid;
            int r = q >> 6, cc = q & 63;
            WbT[(size_t)(kv * 512 + ot + r) * 512 + dt + cc] = (bf16)smem[cc * 65 + r];
        }
    } else if (b < 4096) {
        // prep_arwt: arWT[o][i*512+d] = M[o][d][i]
        int o = b - 3584;
        for (int q = tid; q < 1536; q += 256) smem[q] = M[(size_t)o * 1536 + q];
        __syncthreads();
        for (int q = tid; q < 1536; q += 256) {
            int i = q >> 9, d = q & 511;
            arWT[(size_t)o * 1536 + q] = (bf16)smem[d * 3 + i];
        }
    } else {
        // prep_tb, 8 j's per thread: Tb[kv][m][i][j] = phi_kv[m*128+i-j]
        int idx8 = (b - 4096) * 256 + tid;   // over 48*16*128*16
        int j8 = (idx8 & 15) * 8;
        int i  = (idx8 >> 4) & 127;
        int m  = (idx8 >> 11) & 15;
        int kv = idx8 >> 15;
        int k  = (kv >= 24) ? kv - 24 : kv;
        bf16x8 v;
#pragma unroll
        for (int jj = 0; jj < 8; ++jj) {
            int sh = m * 128 + i - (j8 + jj);
            float f = 0.f;
            if (sh >= 0) {
                f = phi[sh * 24 + k];
                if (kv >= 24 && (sh & 1)) f = -f;
            }
            v[jj] = (bf16)f;
        }
        *(bf16x8*)(Tb + (size_t)idx8 * 8) = v;
    }
}

// ---------------------------------------------------------------------------
// Launch
// ---------------------------------------------------------------------------
extern "C" void kernel_launch(void* const* d_in, const int* in_sizes, int n_in,
                              void* d_out, int out_size, void* d_ws, size_t ws_size,
                              hipStream_t stream) {
    const float* x   = (const float*)d_in[0];
    const float* phi = (const float*)d_in[1];
    const float* M   = (const float*)d_in[2];
    const float* Mp  = (const float*)d_in[3];
    const float* Mm  = (const float*)d_in[4];
    float* out = (float*)d_out;
    char* ws = (char*)d_ws;

    // workspace layout (bytes)
    bf16*  WbT  = (bf16*)(ws + 0);          //  25,165,824
    bf16*  Tb   = (bf16*)(ws + 25165824);   //  25,165,824
    bf16*  xb   = (bf16*)(ws + 50331648);   //   2,097,152
    bf16*  xar  = (bf16*)(ws + 52428800);   //   6,291,456
    bf16*  arWT = (bf16*)(ws + 58720256);   //   1,572,864
    bf16*  YT   = (bf16*)(ws + 60293120);   // 100,663,296  (total 160,956,416)

    hipMemsetAsync(d_out, 0, (size_t)out_size * sizeof(float), stream);
    prep_all<<<10240, 256, 0, stream>>>(x, phi, M, Mp, Mm, xb, xar, WbT, arWT, Tb);
    yt_gemm<<<dim3(192, 16), 256, 0, stream>>>(WbT, xb, YT);
    conv_gemm<<<2176, 256, 0, stream>>>(Tb, YT, out);
    ar_gemm<<<dim3(16, 4), 256, 0, stream>>>(xar, arWT, out);
}

// Round 5
// 401.510 us; speedup vs baseline: 1.0757x; 1.0757x over previous
//
#include <hip/hip_runtime.h>

typedef __bf16 bf16;
typedef bf16 bf16x8 __attribute__((ext_vector_type(8)));
typedef float floatx4 __attribute__((ext_vector_type(4)));

#define AS1 __attribute__((address_space(1)))
#define AS3 __attribute__((address_space(3)))

// ---------------------------------------------------------------------------
// Core tile machinery: 128x128 block, 4 waves (2x2 of 64x64), BK=64,
// 16x16x32 bf16 MFMA. Both operands stored [row][k] (k-contiguous).
// Staging: global_load_lds width=16, lane-contiguous LDS, XOR swizzle applied
// to the GLOBAL column so ds_read_b128 fragment loads are conflict-free.
// ---------------------------------------------------------------------------
__device__ __forceinline__ void stage_tile(const bf16* g, int ld, bf16* lds, int tid) {
#pragma unroll
    for (int it = 0; it < 4; ++it) {
        int q    = it * 256 + tid;        // 0..1023, 8 bf16 per q
        int row  = q >> 3;
        int col8 = (q & 7) ^ (row & 7);   // swizzle on global side
        __builtin_amdgcn_global_load_lds(
            (const AS1 void*)(g + (size_t)row * ld + col8 * 8),
            (AS3 void*)(lds + q * 8), 16, 0, 0);
    }
}

__device__ __forceinline__ void mfma_block(const bf16* lA, const bf16* lB,
                                           floatx4 acc[4][4], int lane, int wm, int wn) {
    const int lrow = lane & 15;
    const int lk   = lane >> 4;
#pragma unroll
    for (int s = 0; s < 2; ++s) {   // two K=32 steps per BK=64
        bf16x8 af[4], bfr[4];
        const int c8 = s * 4 + lk;
#pragma unroll
        for (int mi = 0; mi < 4; ++mi) {
            int r = wm * 64 + mi * 16 + lrow;
            af[mi] = *(const bf16x8*)(lA + r * 64 + ((c8 ^ (r & 7)) << 3));
        }
#pragma unroll
        for (int ni = 0; ni < 4; ++ni) {
            int r = wn * 64 + ni * 16 + lrow;
            bfr[ni] = *(const bf16x8*)(lB + r * 64 + ((c8 ^ (r & 7)) << 3));
        }
#pragma unroll
        for (int mi = 0; mi < 4; ++mi)
#pragma unroll
            for (int ni = 0; ni < 4; ++ni)
                acc[mi][ni] = __builtin_amdgcn_mfma_f32_16x16x32_bf16(
                    af[mi], bfr[ni], acc[mi][ni], 0, 0, 0);
    }
}

// S(a,n) = 48*(a+1)*(2a+n): start of tile (a,n) in the flattened slice space.
__device__ __forceinline__ int tile_start(int a, int n) {
    return 48 * (a + 1) * (2 * a + n);
}

// ---------------------------------------------------------------------------
// GEMM1: YT[kv*512+o][t] = sum_d WbT[kv*512+o][d] * xb[t][d]
// Grid (16,192): bn fast so 16 consecutive blocks share one A tile (L2 reuse).
// ---------------------------------------------------------------------------
__global__ __launch_bounds__(256) void yt_gemm(const bf16* __restrict__ WbT,
                                               const bf16* __restrict__ xb,
                                               bf16* __restrict__ YT) {
    __shared__ bf16 lA[128 * 64], lB[128 * 64];
    const int tid = threadIdx.x;
    const int lane = tid & 63, wave = tid >> 6, wm = wave & 1, wn = wave >> 1;
    const int bn = blockIdx.x, bm = blockIdx.y;
    const bf16* Ab = WbT + (size_t)bm * 128 * 512;
    const bf16* Bb = xb + (size_t)bn * 128 * 512;

    floatx4 acc[4][4];
    floatx4 zero = {0.f, 0.f, 0.f, 0.f};
#pragma unroll
    for (int mi = 0; mi < 4; ++mi)
#pragma unroll
        for (int ni = 0; ni < 4; ++ni) acc[mi][ni] = zero;

    for (int kk = 0; kk < 512; kk += 64) {
        stage_tile(Ab + kk, 512, lA, tid);
        stage_tile(Bb + kk, 512, lB, tid);
        __syncthreads();
        mfma_block(lA, lB, acc, lane, wm, wn);
        __syncthreads();
    }
#pragma unroll
    for (int mi = 0; mi < 4; ++mi)
#pragma unroll
        for (int ni = 0; ni < 4; ++ni)
#pragma unroll
            for (int r = 0; r < 4; ++r) {
                int ko = bm * 128 + wm * 64 + mi * 16 + (lane >> 4) * 4 + r;
                int t  = bn * 128 + wn * 64 + ni * 16 + (lane & 15);
                YT[(size_t)ko * 2048 + t] = (bf16)acc[mi][ni][r];
            }
}

// ---------------------------------------------------------------------------
// Stream-K conv GEMM. Slice space: tiles (a asc, n asc), size 48*(a+1) each,
// total 26112 = 768 * 34. Block g owns slices [34g, 34g+34) -> exactly one
// residency round (3 blocks/CU), zero tail. Each maximal run inside a tile is
// flushed as one fp32 128x128 partial to P[seg], seg globally numbered:
// idx(x) = ceil(x/34) + #{tile starts < x not divisible by 34}.
// ---------------------------------------------------------------------------
__global__ __launch_bounds__(256) void conv_gemm(const bf16* __restrict__ Tb,
                                                 const bf16* __restrict__ YT,
                                                 float* __restrict__ P) {
    __shared__ bf16 lA[128 * 64], lB[128 * 64];
    const int tid = threadIdx.x;
    const int lane = tid & 63, wave = tid >> 6, wm = wave & 1, wn = wave >> 1;
    const int g = blockIdx.x;
    int s = g * 34;
    const int send = s + 34;

    // decode starting tile
    int a = 0;
    while (96 * (a + 1) * (a + 2) <= s) ++a;
    int rem = s - 96 * a * (a + 1);
    int width = 48 * (a + 1);
    int n = rem / width;
    int sl = rem - n * width;

    // global segment index of this block's first segment
    int seg = g;
    for (int j = 1; j < 64; ++j) {
        int Sj = tile_start(j >> 2, j & 3);
        seg += (Sj < s && (Sj % 34) != 0) ? 1 : 0;
    }

    floatx4 acc[4][4];
    floatx4 zero = {0.f, 0.f, 0.f, 0.f};
#pragma unroll
    for (int mi = 0; mi < 4; ++mi)
#pragma unroll
        for (int ni = 0; ni < 4; ++ni) acc[mi][ni] = zero;

    while (true) {
        int take = send - s;
        if (width - sl < take) take = width - sl;
        int c = sl / 48, kv = sl - c * 48;
        for (int q = 0; q < take; ++q) {
            const bf16* Ab = Tb + ((size_t)kv * 16 + (a - c)) * 16384;
            const bf16* Bb = YT + (size_t)(kv * 512 + n * 128) * 2048 + c * 128;
#pragma unroll
            for (int kk = 0; kk < 128; kk += 64) {
                stage_tile(Ab + kk, 128, lA, tid);
                stage_tile(Bb + kk, 2048, lB, tid);
                __syncthreads();
                mfma_block(lA, lB, acc, lane, wm, wn);
                __syncthreads();
            }
            if (++kv == 48) { kv = 0; ++c; }
        }
        // flush partial tile
        float* Pt = P + (size_t)seg * 16384;
#pragma unroll
        for (int mi = 0; mi < 4; ++mi)
#pragma unroll
            for (int ni = 0; ni < 4; ++ni)
#pragma unroll
                for (int r = 0; r < 4; ++r) {
                    int row = wm * 64 + mi * 16 + (lane >> 4) * 4 + r;  // t-local
                    int col = wn * 64 + ni * 16 + (lane & 15);          // o-local
                    Pt[row * 128 + col] = acc[mi][ni][r];
                }
        ++seg;
        s += take;
        if (s >= send) break;
        // advance to next tile
        sl = 0;
        if (++n == 4) { n = 0; ++a; }
        width = 48 * (a + 1);
#pragma unroll
        for (int mi = 0; mi < 4; ++mi)
#pragma unroll
            for (int ni = 0; ni < 4; ++ni) acc[mi][ni] = zero;
    }
}

// ---------------------------------------------------------------------------
// AR GEMM, K-split x4: PAR[sp][t][o] = partial over K range [sp*384,(sp+1)*384)
// ---------------------------------------------------------------------------
__global__ __launch_bounds__(256) void ar_gemm(const bf16* __restrict__ xar,
                                               const bf16* __restrict__ arWT,
                                               float* __restrict__ PAR) {
    __shared__ bf16 lA[128 * 64], lB[128 * 64];
    const int tid = threadIdx.x;
    const int lane = tid & 63, wave = tid >> 6, wm = wave & 1, wn = wave >> 1;
    const int bm = blockIdx.x, bn = blockIdx.y, sp = blockIdx.z;
    const bf16* Ab = xar + (size_t)bm * 128 * 1536 + sp * 384;
    const bf16* Bb = arWT + (size_t)bn * 128 * 1536 + sp * 384;

    floatx4 acc[4][4];
    floatx4 zero = {0.f, 0.f, 0.f, 0.f};
#pragma unroll
    for (int mi = 0; mi < 4; ++mi)
#pragma unroll
        for (int ni = 0; ni < 4; ++ni) acc[mi][ni] = zero;

    for (int kk = 0; kk < 384; kk += 64) {
        stage_tile(Ab + kk, 1536, lA, tid);
        stage_tile(Bb + kk, 1536, lB, tid);
        __syncthreads();
        mfma_block(lA, lB, acc, lane, wm, wn);
        __syncthreads();
    }
    float* Pt = PAR + (size_t)sp * 1048576;
#pragma unroll
    for (int mi = 0; mi < 4; ++mi)
#pragma unroll
        for (int ni = 0; ni < 4; ++ni)
#pragma unroll
            for (int r = 0; r < 4; ++r) {
                int t = bm * 128 + wm * 64 + mi * 16 + (lane >> 4) * 4 + r;
                int o = bn * 128 + wn * 64 + ni * 16 + (lane & 15);
                Pt[(size_t)t * 512 + o] = acc[mi][ni][r];
            }
}

// ---------------------------------------------------------------------------
// Fused prep: block ranges dispatch prep_x / prep_wbt / prep_arwt / prep_tb
// ---------------------------------------------------------------------------
__global__ void prep_all(const float* __restrict__ x, const float* __restrict__ phi,
                         const float* __restrict__ M, const float* __restrict__ Mp,
                         const float* __restrict__ Mm, bf16* __restrict__ xb,
                         bf16* __restrict__ xar, bf16* __restrict__ WbT,
                         bf16* __restrict__ arWT, bf16* __restrict__ Tb) {
    __shared__ float smem[64 * 65];
    const int b = blockIdx.x, tid = threadIdx.x;
    if (b < 512) {
        // prep_x, 8 d's per thread: idx8 over 2048*64
        int idx8 = b * 256 + tid;
        int t = idx8 >> 6, d8 = (idx8 & 63) * 8;
        const float* xp = x + (size_t)t * 512 + d8;
        bf16x8 v;
#pragma unroll
        for (int jj = 0; jj < 8; ++jj) v[jj] = (bf16)xp[jj];
        *(bf16x8*)(xb + (size_t)t * 512 + d8) = v;
#pragma unroll
        for (int i = 0; i < 3; ++i) {
            bf16x8 w;
            if (t - i >= 0) {
                const float* xq = xp - (size_t)i * 512;
#pragma unroll
                for (int jj = 0; jj < 8; ++jj) w[jj] = (bf16)xq[jj];
            } else {
#pragma unroll
                for (int jj = 0; jj < 8; ++jj) w[jj] = (bf16)0.f;
            }
            *(bf16x8*)(xar + (size_t)t * 1536 + i * 512 + d8) = w;
        }
    } else if (b < 3584) {
        // prep_wbt: WbT[(kv*512+o)][d] = Mp/Mm[k][d][o] via 64x64 LDS transpose
        int b2 = b - 512;
        int kv = b2 >> 6, rem = b2 & 63;
        int dt = (rem >> 3) * 64, ot = (rem & 7) * 64;
        const float* src = (kv < 24) ? (Mp + (size_t)kv * 262144)
                                     : (Mm + (size_t)(kv - 24) * 262144);
#pragma unroll
        for (int it = 0; it < 16; ++it) {
            int q = it * 256 + tid;
            int r = q >> 6, cc = q & 63;
            smem[r * 65 + cc] = src[(size_t)(dt + r) * 512 + ot + cc];
        }
        __syncthreads();
#pragma unroll
        for (int it = 0; it < 16; ++it) {
            int q = it * 256 + tid;
            int r = q >> 6, cc = q & 63;
            WbT[(size_t)(kv * 512 + ot + r) * 512 + dt + cc] = (bf16)smem[cc * 65 + r];
        }
    } else if (b < 4096) {
        // prep_arwt: arWT[o][i*512+d] = M[o][d][i]
        int o = b - 3584;
        for (int q = tid; q < 1536; q += 256) smem[q] = M[(size_t)o * 1536 + q];
        __syncthreads();
        for (int q = tid; q < 1536; q += 256) {
            int i = q >> 9, d = q & 511;
            arWT[(size_t)o * 1536 + q] = (bf16)smem[d * 3 + i];
        }
    } else {
        // prep_tb, 8 j's per thread: Tb[kv][m][i][j] = phi_kv[m*128+i-j]
        int idx8 = (b - 4096) * 256 + tid;   // over 48*16*128*16
        int j8 = (idx8 & 15) * 8;
        int i  = (idx8 >> 4) & 127;
        int m  = (idx8 >> 11) & 15;
        int kv = idx8 >> 15;
        int k  = (kv >= 24) ? kv - 24 : kv;
        bf16x8 v;
#pragma unroll
        for (int jj = 0; jj < 8; ++jj) {
            int sh = m * 128 + i - (j8 + jj);
            float f = 0.f;
            if (sh >= 0) {
                f = phi[sh * 24 + k];
                if (kv >= 24 && (sh & 1)) f = -f;
            }
            v[jj] = (bf16)f;
        }
        *(bf16x8*)(Tb + (size_t)idx8 * 8) = v;
    }
}

// ---------------------------------------------------------------------------
// reduce: out[t][o] = sum_sp PAR[sp][t][o] + sum of conv segments for tile
// ---------------------------------------------------------------------------
__global__ void reduce_out(const float* __restrict__ P, const float* __restrict__ PAR,
                           float* __restrict__ out) {
    int idx = blockIdx.x * 256 + threadIdx.x;   // over 2048*512
    if (idx >= 2048 * 512) return;
    int t = idx >> 9, o = idx & 511;
    int a = t >> 7, i = t & 127, n = o >> 7, ol = o & 127;
    int S = tile_start(a, n);
    int E = S + 48 * (a + 1);
    int i0 = (S + 33) / 34, i1 = (E + 33) / 34;
    for (int j = 1; j < 64; ++j) {
        int Sj = tile_start(j >> 2, j & 3);
        if ((Sj % 34) != 0) {
            i0 += (Sj < S) ? 1 : 0;
            i1 += (Sj < E) ? 1 : 0;
        }
    }
    float s = PAR[idx] + PAR[idx + 1048576] + PAR[idx + 2097152] + PAR[idx + 3145728];
    for (int k = i0; k < i1; ++k)
        s += P[(size_t)k * 16384 + i * 128 + ol];
    out[idx] = s;
}

// ---------------------------------------------------------------------------
// Launch
// ---------------------------------------------------------------------------
extern "C" void kernel_launch(void* const* d_in, const int* in_sizes, int n_in,
                              void* d_out, int out_size, void* d_ws, size_t ws_size,
                              hipStream_t stream) {
    const float* x   = (const float*)d_in[0];
    const float* phi = (const float*)d_in[1];
    const float* M   = (const float*)d_in[2];
    const float* Mp  = (const float*)d_in[3];
    const float* Mm  = (const float*)d_in[4];
    float* out = (float*)d_out;
    char* ws = (char*)d_ws;

    // workspace layout (bytes)
    bf16*  WbT  = (bf16*)(ws + 0);          //  25,165,824
    bf16*  Tb   = (bf16*)(ws + 25165824);   //  25,165,824
    bf16*  xb   = (bf16*)(ws + 50331648);   //   2,097,152
    bf16*  xar  = (bf16*)(ws + 52428800);   //   6,291,456
    bf16*  arWT = (bf16*)(ws + 58720256);   //   1,572,864
    bf16*  YT   = (bf16*)(ws + 60293120);   // 100,663,296
    float* P    = (float*)(ws + 160956416); //  54,525,952 (832 segment slots)
    float* PAR  = (float*)(ws + 215482368); //  16,777,216  (total 232,259,584)

    prep_all<<<10240, 256, 0, stream>>>(x, phi, M, Mp, Mm, xb, xar, WbT, arWT, Tb);
    yt_gemm<<<dim3(16, 192), 256, 0, stream>>>(WbT, xb, YT);
    conv_gemm<<<768, 256, 0, stream>>>(Tb, YT, P);
    ar_gemm<<<dim3(16, 4, 4), 256, 0, stream>>>(xar, arWT, PAR);
    reduce_out<<<4096, 256, 0, stream>>>(P, PAR, out);
}

// Round 7
// 346.112 us; speedup vs baseline: 1.2479x; 1.1601x over previous
//
#include <hip/hip_runtime.h>

typedef __bf16 bf16;
typedef bf16 bf16x8 __attribute__((ext_vector_type(8)));
typedef float floatx4 __attribute__((ext_vector_type(4)));

#define AS1 __attribute__((address_space(1)))
#define AS3 __attribute__((address_space(3)))

#define KTOT 26112   // A2/B2 leading dim: 48*512 spectral + 3*512 AR columns

// ---------------------------------------------------------------------------
// Core tile machinery: 128x128 block, 4 waves (2x2 of 64x64), BK=64,
// 16x16x32 bf16 MFMA. Both operands stored [row][k] (k-contiguous).
// Staging: global_load_lds width=16, lane-contiguous LDS, XOR swizzle applied
// to the GLOBAL column so ds_read_b128 fragment loads are conflict-free.
// ---------------------------------------------------------------------------
__device__ __forceinline__ void stage_tile(const bf16* g, int ld, bf16* lds, int tid) {
#pragma unroll
    for (int it = 0; it < 4; ++it) {
        int q    = it * 256 + tid;        // 0..1023, 8 bf16 per q
        int row  = q >> 3;
        int col8 = (q & 7) ^ (row & 7);   // swizzle on global side
        __builtin_amdgcn_global_load_lds(
            (const AS1 void*)(g + (size_t)row * ld + col8 * 8),
            (AS3 void*)(lds + q * 8), 16, 0, 0);
    }
}

__device__ __forceinline__ void mfma_block(const bf16* lA, const bf16* lB,
                                           floatx4 acc[4][4], int lane, int wm, int wn) {
    const int lrow = lane & 15;
    const int lk   = lane >> 4;
#pragma unroll
    for (int s = 0; s < 2; ++s) {   // two K=32 steps per BK=64
        bf16x8 af[4], bfr[4];
        const int c8 = s * 4 + lk;
#pragma unroll
        for (int mi = 0; mi < 4; ++mi) {
            int r = wm * 64 + mi * 16 + lrow;
            af[mi] = *(const bf16x8*)(lA + r * 64 + ((c8 ^ (r & 7)) << 3));
        }
#pragma unroll
        for (int ni = 0; ni < 4; ++ni) {
            int r = wn * 64 + ni * 16 + lrow;
            bfr[ni] = *(const bf16x8*)(lB + r * 64 + ((c8 ^ (r & 7)) << 3));
        }
#pragma unroll
        for (int mi = 0; mi < 4; ++mi)
#pragma unroll
            for (int ni = 0; ni < 4; ++ni)
                acc[mi][ni] = __builtin_amdgcn_mfma_f32_16x16x32_bf16(
                    af[mi], bfr[ni], acc[mi][ni], 0, 0, 0);
    }
}

// ---------------------------------------------------------------------------
// Conv phase: U2 tile per (kf, a, dblk). A = Tb[kf][a-c] (128x128 Toeplitz),
// B = xT rows d (2 MB total, L2-resident). C written bf16 straight into
// A2[t][kf*512 + dblk*128 + d] — each output tile owned by exactly one block.
// Grid 3072, bid ordered a-descending (LPT packing over ~4 rounds).
// ---------------------------------------------------------------------------
__global__ __launch_bounds__(256) void conv_gemm(const bf16* __restrict__ Tb,
                                                 const bf16* __restrict__ xT,
                                                 bf16* __restrict__ A2) {
    __shared__ bf16 lA[128 * 64], lB[128 * 64];
    const int tid = threadIdx.x;
    const int lane = tid & 63, wave = tid >> 6, wm = wave & 1, wn = wave >> 1;
    const int bid = blockIdx.x;
    const int a    = 15 - (bid / 192);      // longest-first
    const int rem  = bid % 192;
    const int kf   = rem >> 2;
    const int dblk = rem & 3;

    floatx4 acc[4][4];
    floatx4 zero = {0.f, 0.f, 0.f, 0.f};
#pragma unroll
    for (int mi = 0; mi < 4; ++mi)
#pragma unroll
        for (int ni = 0; ni < 4; ++ni) acc[mi][ni] = zero;

    for (int c = 0; c <= a; ++c) {
        const bf16* Ab = Tb + ((size_t)kf * 16 + (a - c)) * 16384;
        const bf16* Bb = xT + (size_t)(dblk * 128) * 2048 + c * 128;
#pragma unroll
        for (int kk = 0; kk < 128; kk += 64) {
            stage_tile(Ab + kk, 128, lA, tid);
            stage_tile(Bb + kk, 2048, lB, tid);
            __syncthreads();
            mfma_block(lA, lB, acc, lane, wm, wn);
            __syncthreads();
        }
    }
    // C row = t-local i, col = d-local; write bf16 into A2
    bf16* Ob = A2 + (size_t)(a * 128) * KTOT + kf * 512 + dblk * 128;
#pragma unroll
    for (int mi = 0; mi < 4; ++mi)
#pragma unroll
        for (int ni = 0; ni < 4; ++ni)
#pragma unroll
            for (int r = 0; r < 4; ++r) {
                int row = wm * 64 + mi * 16 + (lane >> 4) * 4 + r;
                int col = wn * 64 + ni * 16 + (lane & 15);
                Ob[(size_t)row * KTOT + col] = (bf16)acc[mi][ni][r];
            }
}

// ---------------------------------------------------------------------------
// Projection GEMM: out[t][o] = sum_K A2[t][K] * B2[o][K], K = 26112
// (48 spectral k-slabs + 3 AR taps). K-split x12 -> grid (16,12,4) = 768
// blocks = exactly one residency round. Partials fp32 to P2[sp].
// ---------------------------------------------------------------------------
__global__ __launch_bounds__(256) void proj_gemm(const bf16* __restrict__ A2,
                                                 const bf16* __restrict__ B2,
                                                 float* __restrict__ P2) {
    __shared__ bf16 lA[128 * 64], lB[128 * 64];
    const int tid = threadIdx.x;
    const int lane = tid & 63, wave = tid >> 6, wm = wave & 1, wn = wave >> 1;
    const int bm = blockIdx.x, sp = blockIdx.y, bn = blockIdx.z;
    const bf16* Ab = A2 + (size_t)bm * 128 * KTOT + sp * 2176;
    const bf16* Bb = B2 + (size_t)bn * 128 * KTOT + sp * 2176;

    floatx4 acc[4][4];
    floatx4 zero = {0.f, 0.f, 0.f, 0.f};
#pragma unroll
    for (int mi = 0; mi < 4; ++mi)
#pragma unroll
        for (int ni = 0; ni < 4; ++ni) acc[mi][ni] = zero;

    for (int kk = 0; kk < 2176; kk += 64) {
        stage_tile(Ab + kk, KTOT, lA, tid);
        stage_tile(Bb + kk, KTOT, lB, tid);
        __syncthreads();
        mfma_block(lA, lB, acc, lane, wm, wn);
        __syncthreads();
    }
    float* Pt = P2 + (size_t)sp * 1048576;
#pragma unroll
    for (int mi = 0; mi < 4; ++mi)
#pragma unroll
        for (int ni = 0; ni < 4; ++ni)
#pragma unroll
            for (int r = 0; r < 4; ++r) {
                int t = bm * 128 + wm * 64 + mi * 16 + (lane >> 4) * 4 + r;
                int o = bn * 128 + wn * 64 + ni * 16 + (lane & 15);
                Pt[(size_t)t * 512 + o] = acc[mi][ni][r];
            }
}

// ---------------------------------------------------------------------------
// Fused prep: xT transpose / A2-AR fill / B2 spectral transpose / B2-AR / Tb
// ---------------------------------------------------------------------------
__global__ void prep_all(const float* __restrict__ x, const float* __restrict__ phi,
                         const float* __restrict__ M, const float* __restrict__ Mp,
                         const float* __restrict__ Mm, bf16* __restrict__ xT,
                         bf16* __restrict__ A2, bf16* __restrict__ B2,
                         bf16* __restrict__ Tb) {
    __shared__ float smem[64 * 65];
    const int b = blockIdx.x, tid = threadIdx.x;
    if (b < 256) {
        // xT[d][t] = x[t][d], 64x64 LDS transpose tiles
        int tt = (b >> 3) * 64, dd = (b & 7) * 64;
#pragma unroll
        for (int it = 0; it < 16; ++it) {
            int q = it * 256 + tid;
            int r = q >> 6, cc = q & 63;   // r = t-local, cc = d-local
            smem[r * 65 + cc] = x[(size_t)(tt + r) * 512 + dd + cc];
        }
        __syncthreads();
#pragma unroll
        for (int it = 0; it < 16; ++it) {
            int q = it * 256 + tid;
            int r = q >> 6, cc = q & 63;   // r = d-local, cc = t-local
            xT[(size_t)(dd + r) * 2048 + tt + cc] = (bf16)smem[cc * 65 + r];
        }
    } else if (b < 1792) {
        // A2 AR columns: A2[t][24576 + i*512 + d] = x[t-i][d]
        int idx8 = (b - 256) * 256 + tid;   // over 2048*192
        int t = idx8 / 192, q = idx8 % 192;
        int i = q >> 6, d8 = (q & 63) * 8;
        bf16x8 v;
        if (t - i >= 0) {
            const float* xp = x + (size_t)(t - i) * 512 + d8;
#pragma unroll
            for (int jj = 0; jj < 8; ++jj) v[jj] = (bf16)xp[jj];
        } else {
#pragma unroll
            for (int jj = 0; jj < 8; ++jj) v[jj] = (bf16)0.f;
        }
        *(bf16x8*)(A2 + (size_t)t * KTOT + 24576 + i * 512 + d8) = v;
    } else if (b < 4864) {
        // B2[o][kv*512+d] = Mp/Mm[kv][d][o], 64x64 LDS transpose
        int b2 = b - 1792;
        int kv = b2 >> 6, rem = b2 & 63;
        int dt = (rem >> 3) * 64, ot = (rem & 7) * 64;
        const float* src = (kv < 24) ? (Mp + (size_t)kv * 262144)
                                     : (Mm + (size_t)(kv - 24) * 262144);
#pragma unroll
        for (int it = 0; it < 16; ++it) {
            int q = it * 256 + tid;
            int r = q >> 6, cc = q & 63;   // r = d-local, cc = o-local
            smem[r * 65 + cc] = src[(size_t)(dt + r) * 512 + ot + cc];
        }
        __syncthreads();
#pragma unroll
        for (int it = 0; it < 16; ++it) {
            int q = it * 256 + tid;
            int r = q >> 6, cc = q & 63;   // r = o-local, cc = d-local
            B2[(size_t)(ot + r) * KTOT + kv * 512 + dt + cc] = (bf16)smem[cc * 65 + r];
        }
    } else if (b < 5376) {
        // B2 AR columns: B2[o][24576 + i*512 + d] = M[o][d][i]
        int o = b - 4864;
        for (int q = tid; q < 1536; q += 256) smem[q] = M[(size_t)o * 1536 + q];
        __syncthreads();
        for (int q = tid; q < 1536; q += 256) {
            int i = q >> 9, d = q & 511;
            B2[(size_t)o * KTOT + 24576 + q] = (bf16)smem[d * 3 + i];
        }
    } else {
        // Tb[kv][m][i][j] = phi_kv[m*128+i-j], alt-sign for kv>=24; 8 j/thread
        int idx8 = (b - 5376) * 256 + tid;   // over 48*16*128*16
        int j8 = (idx8 & 15) * 8;
        int i  = (idx8 >> 4) & 127;
        int m  = (idx8 >> 11) & 15;
        int kv = idx8 >> 15;
        int k  = (kv >= 24) ? kv - 24 : kv;
        bf16x8 v;
#pragma unroll
        for (int jj = 0; jj < 8; ++jj) {
            int sh = m * 128 + i - (j8 + jj);
            float f = 0.f;
            if (sh >= 0) {
                f = phi[sh * 24 + k];
                if (kv >= 24 && (sh & 1)) f = -f;
            }
            v[jj] = (bf16)f;
        }
        *(bf16x8*)(Tb + (size_t)idx8 * 8) = v;
    }
}

// ---------------------------------------------------------------------------
// reduce: out = sum of 12 K-split partials
// ---------------------------------------------------------------------------
__global__ void reduce12(const float* __restrict__ P2, float* __restrict__ out) {
    int idx = blockIdx.x * 256 + threadIdx.x;   // over 2048*512
    if (idx >= 2048 * 512) return;
    float s = 0.f;
#pragma unroll
    for (int sp = 0; sp < 12; ++sp)
        s += P2[(size_t)sp * 1048576 + idx];
    out[idx] = s;
}

// ---------------------------------------------------------------------------
// Launch
// ---------------------------------------------------------------------------
extern "C" void kernel_launch(void* const* d_in, const int* in_sizes, int n_in,
                              void* d_out, int out_size, void* d_ws, size_t ws_size,
                              hipStream_t stream) {
    const float* x   = (const float*)d_in[0];
    const float* phi = (const float*)d_in[1];
    const float* M   = (const float*)d_in[2];
    const float* Mp  = (const float*)d_in[3];
    const float* Mm  = (const float*)d_in[4];
    float* out = (float*)d_out;
    char* ws = (char*)d_ws;

    // workspace layout (bytes)
    bf16*  Tb = (bf16*)(ws + 0);           //  25,165,824
    bf16*  xT = (bf16*)(ws + 25165824);    //   2,097,152
    bf16*  A2 = (bf16*)(ws + 27262976);    // 106,954,752  [2048 x 26112]
    bf16*  B2 = (bf16*)(ws + 134217728);   //  26,738,688  [ 512 x 26112]
    float* P2 = (float*)(ws + 160956416);  //  50,331,648  [12 x 2048 x 512]
                                           //  total 211,288,064

    prep_all<<<11520, 256, 0, stream>>>(x, phi, M, Mp, Mm, xT, A2, B2, Tb);
    conv_gemm<<<3072, 256, 0, stream>>>(Tb, xT, A2);
    proj_gemm<<<dim3(16, 12, 4), 256, 0, stream>>>(A2, B2, P2);
    reduce12<<<4096, 256, 0, stream>>>(P2, out);
}

// Round 9
// 297.705 us; speedup vs baseline: 1.4508x; 1.1626x over previous
//
#include <hip/hip_runtime.h>

typedef __bf16 bf16;
typedef bf16 bf16x8 __attribute__((ext_vector_type(8)));
typedef float floatx16 __attribute__((ext_vector_type(16)));

#define AS1 __attribute__((address_space(1)))
#define AS3 __attribute__((address_space(3)))

#define KTOT 26112   // A2/B2 leading dim: 48*512 spectral + 3*512 AR columns

// ---------------------------------------------------------------------------
// Core tile machinery: 128x128 block, 4 waves (2x2 of 64x64), BK=64,
// 32x32x16 bf16 MFMA (2x2 tiles/wave, 16 MFMA per BK vs 32 for 16x16x32).
// Staging: global_load_lds width=16, lane-contiguous LDS, XOR swizzle applied
// to the GLOBAL column so ds_read_b128 fragment loads are conflict-free.
// ---------------------------------------------------------------------------
__device__ __forceinline__ void stage_tile(const bf16* g, int ld, bf16* lds, int tid) {
#pragma unroll
    for (int it = 0; it < 4; ++it) {
        int q    = it * 256 + tid;        // 0..1023, 8 bf16 per q
        int row  = q >> 3;
        int col8 = (q & 7) ^ (row & 7);   // swizzle on global side
        __builtin_amdgcn_global_load_lds(
            (const AS1 void*)(g + (size_t)row * ld + col8 * 8),
            (AS3 void*)(lds + q * 8), 16, 0, 0);
    }
}

// A frag (M=32,K=16): m=lane&31, k=8*(lane>>5)+j. B symmetric. 4 K-steps/BK.
__device__ __forceinline__ void mfma_block(const bf16* lA, const bf16* lB,
                                           floatx16 acc[2][2], int lane, int wm, int wn) {
    const int lrow = lane & 31;
    const int lk   = lane >> 5;
#pragma unroll
    for (int s = 0; s < 4; ++s) {   // four K=16 steps per BK=64
        bf16x8 af[2], bfr[2];
        const int c8 = s * 2 + lk;
#pragma unroll
        for (int mi = 0; mi < 2; ++mi) {
            int r = wm * 64 + mi * 32 + lrow;
            af[mi] = *(const bf16x8*)(lA + r * 64 + ((c8 ^ (r & 7)) << 3));
        }
#pragma unroll
        for (int ni = 0; ni < 2; ++ni) {
            int r = wn * 64 + ni * 32 + lrow;
            bfr[ni] = *(const bf16x8*)(lB + r * 64 + ((c8 ^ (r & 7)) << 3));
        }
#pragma unroll
        for (int mi = 0; mi < 2; ++mi)
#pragma unroll
            for (int ni = 0; ni < 2; ++ni)
                acc[mi][ni] = __builtin_amdgcn_mfma_f32_32x32x16_bf16(
                    af[mi], bfr[ni], acc[mi][ni], 0, 0, 0);
    }
}

// C/D mapping for 32x32 (m74/m101): col=lane&31, row=(r&3)+8*(r>>2)+4*(lane>>5)
#define CD_ROW(r, lane) (((r) & 3) + 8 * ((r) >> 2) + 4 * ((lane) >> 5))

// ---------------------------------------------------------------------------
// Conv phase: U2 tile per (kf, a, dblk). A = Tb[kf][a-c] (128x128 Toeplitz),
// B = xT rows d (2 MB total, L2-resident). C written bf16 straight into
// A2[t][kf*512 + dblk*128 + d]. Grid 3072, a-descending (LPT packing).
// ---------------------------------------------------------------------------
__global__ __launch_bounds__(256) void conv_gemm(const bf16* __restrict__ Tb,
                                                 const bf16* __restrict__ xT,
                                                 bf16* __restrict__ A2) {
    __shared__ bf16 lA[128 * 64], lB[128 * 64];
    const int tid = threadIdx.x;
    const int lane = tid & 63, wave = tid >> 6, wm = wave & 1, wn = wave >> 1;
    const int bid = blockIdx.x;
    const int a    = 15 - (bid / 192);      // longest-first
    const int rem  = bid % 192;
    const int kf   = rem >> 2;
    const int dblk = rem & 3;

    floatx16 acc[2][2];
#pragma unroll
    for (int mi = 0; mi < 2; ++mi)
#pragma unroll
        for (int ni = 0; ni < 2; ++ni)
#pragma unroll
            for (int e = 0; e < 16; ++e) acc[mi][ni][e] = 0.f;

    for (int c = 0; c <= a; ++c) {
        const bf16* Ab = Tb + ((size_t)kf * 16 + (a - c)) * 16384;
        const bf16* Bb = xT + (size_t)(dblk * 128) * 2048 + c * 128;
#pragma unroll
        for (int kk = 0; kk < 128; kk += 64) {
            stage_tile(Ab + kk, 128, lA, tid);
            stage_tile(Bb + kk, 2048, lB, tid);
            __syncthreads();
            mfma_block(lA, lB, acc, lane, wm, wn);
            __syncthreads();
        }
    }
    bf16* Ob = A2 + (size_t)(a * 128) * KTOT + kf * 512 + dblk * 128;
#pragma unroll
    for (int mi = 0; mi < 2; ++mi)
#pragma unroll
        for (int ni = 0; ni < 2; ++ni)
#pragma unroll
            for (int r = 0; r < 16; ++r) {
                int row = wm * 64 + mi * 32 + CD_ROW(r, lane);
                int col = wn * 64 + ni * 32 + (lane & 31);
                Ob[(size_t)row * KTOT + col] = (bf16)acc[mi][ni][r];
            }
}

// ---------------------------------------------------------------------------
// Projection GEMM: out[t][o] = sum_K A2[t][K] * B2[o][K], K = 26112.
// K-split x12 -> grid (16,12,4) = 768 blocks = one residency round.
// ---------------------------------------------------------------------------
__global__ __launch_bounds__(256) void proj_gemm(const bf16* __restrict__ A2,
                                                 const bf16* __restrict__ B2,
                                                 float* __restrict__ P2) {
    __shared__ bf16 lA[128 * 64], lB[128 * 64];
    const int tid = threadIdx.x;
    const int lane = tid & 63, wave = tid >> 6, wm = wave & 1, wn = wave >> 1;
    const int bm = blockIdx.x, sp = blockIdx.y, bn = blockIdx.z;
    const bf16* Ab = A2 + (size_t)bm * 128 * KTOT + sp * 2176;
    const bf16* Bb = B2 + (size_t)bn * 128 * KTOT + sp * 2176;

    floatx16 acc[2][2];
#pragma unroll
    for (int mi = 0; mi < 2; ++mi)
#pragma unroll
        for (int ni = 0; ni < 2; ++ni)
#pragma unroll
            for (int e = 0; e < 16; ++e) acc[mi][ni][e] = 0.f;

    for (int kk = 0; kk < 2176; kk += 64) {
        stage_tile(Ab + kk, KTOT, lA, tid);
        stage_tile(Bb + kk, KTOT, lB, tid);
        __syncthreads();
        mfma_block(lA, lB, acc, lane, wm, wn);
        __syncthreads();
    }
    float* Pt = P2 + (size_t)sp * 1048576;
#pragma unroll
    for (int mi = 0; mi < 2; ++mi)
#pragma unroll
        for (int ni = 0; ni < 2; ++ni)
#pragma unroll
            for (int r = 0; r < 16; ++r) {
                int t = bm * 128 + wm * 64 + mi * 32 + CD_ROW(r, lane);
                int o = bn * 128 + wn * 64 + ni * 32 + (lane & 31);
                Pt[(size_t)t * 512 + o] = acc[mi][ni][r];
            }
}

// ---------------------------------------------------------------------------
// Fused prep: xT transpose / A2-AR fill / B2 spectral transpose / B2-AR /
// Tb fill (LDS-staged phi, one block per (kv,m))
// ---------------------------------------------------------------------------
__global__ void prep_all(const float* __restrict__ x, const float* __restrict__ phi,
                         const float* __restrict__ M, const float* __restrict__ Mp,
                         const float* __restrict__ Mm, bf16* __restrict__ xT,
                         bf16* __restrict__ A2, bf16* __restrict__ B2,
                         bf16* __restrict__ Tb) {
    __shared__ float smem[64 * 65];
    const int b = blockIdx.x, tid = threadIdx.x;
    if (b < 256) {
        // xT[d][t] = x[t][d], 64x64 LDS transpose tiles
        int tt = (b >> 3) * 64, dd = (b & 7) * 64;
#pragma unroll
        for (int it = 0; it < 16; ++it) {
            int q = it * 256 + tid;
            int r = q >> 6, cc = q & 63;   // r = t-local, cc = d-local
            smem[r * 65 + cc] = x[(size_t)(tt + r) * 512 + dd + cc];
        }
        __syncthreads();
#pragma unroll
        for (int it = 0; it < 16; ++it) {
            int q = it * 256 + tid;
            int r = q >> 6, cc = q & 63;   // r = d-local, cc = t-local
            xT[(size_t)(dd + r) * 2048 + tt + cc] = (bf16)smem[cc * 65 + r];
        }
    } else if (b < 1792) {
        // A2 AR columns: A2[t][24576 + i*512 + d] = x[t-i][d]
        int idx8 = (b - 256) * 256 + tid;   // over 2048*192
        int t = idx8 / 192, q = idx8 % 192;
        int i = q >> 6, d8 = (q & 63) * 8;
        bf16x8 v;
        if (t - i >= 0) {
            const float* xp = x + (size_t)(t - i) * 512 + d8;
#pragma unroll
            for (int jj = 0; jj < 8; ++jj) v[jj] = (bf16)xp[jj];
        } else {
#pragma unroll
            for (int jj = 0; jj < 8; ++jj) v[jj] = (bf16)0.f;
        }
        *(bf16x8*)(A2 + (size_t)t * KTOT + 24576 + i * 512 + d8) = v;
    } else if (b < 4864) {
        // B2[o][kv*512+d] = Mp/Mm[kv][d][o], 64x64 LDS transpose
        int b2 = b - 1792;
        int kv = b2 >> 6, rem = b2 & 63;
        int dt = (rem >> 3) * 64, ot = (rem & 7) * 64;
        const float* src = (kv < 24) ? (Mp + (size_t)kv * 262144)
                                     : (Mm + (size_t)(kv - 24) * 262144);
#pragma unroll
        for (int it = 0; it < 16; ++it) {
            int q = it * 256 + tid;
            int r = q >> 6, cc = q & 63;   // r = d-local, cc = o-local
            smem[r * 65 + cc] = src[(size_t)(dt + r) * 512 + ot + cc];
        }
        __syncthreads();
#pragma unroll
        for (int it = 0; it < 16; ++it) {
            int q = it * 256 + tid;
            int r = q >> 6, cc = q & 63;   // r = o-local, cc = d-local
            B2[(size_t)(ot + r) * KTOT + kv * 512 + dt + cc] = (bf16)smem[cc * 65 + r];
        }
    } else if (b < 5376) {
        // B2 AR columns: B2[o][24576 + i*512 + d] = M[o][d][i]
        int o = b - 4864;
        for (int q = tid; q < 1536; q += 256) smem[q] = M[(size_t)o * 1536 + q];
        __syncthreads();
        for (int q = tid; q < 1536; q += 256) {
            int i = q >> 9, d = q & 511;
            B2[(size_t)o * KTOT + 24576 + q] = (bf16)smem[d * 3 + i];
        }
    } else {
        // Tb fill, one block per (kv,m): Tb[kv][m][i][j] = phi_kv[m*128+i-j].
        // Stage the 255 needed phi values (signed) in LDS, then 16B stores.
        int b3 = b - 5376;              // 0..767
        int kv = b3 >> 4, m = b3 & 15;
        int k  = (kv >= 24) ? kv - 24 : kv;
        if (tid < 255) {
            int sh = m * 128 - 127 + tid;
            float f = 0.f;
            if (sh >= 0) {
                f = phi[sh * 24 + k];
                if (kv >= 24 && (sh & 1)) f = -f;
            }
            smem[tid] = f;
        }
        __syncthreads();
        bf16* Tp = Tb + (size_t)b3 * 16384;
#pragma unroll
        for (int it = 0; it < 8; ++it) {
            int q = it * 256 + tid;     // over 128 i x 16 j8
            int i = q >> 4, j8 = (q & 15) * 8;
            bf16x8 v;
#pragma unroll
            for (int jj = 0; jj < 8; ++jj)
                v[jj] = (bf16)smem[127 + i - (j8 + jj)];
            *(bf16x8*)(Tp + i * 128 + j8) = v;
        }
    }
}

// ---------------------------------------------------------------------------
// reduce: out = sum of 12 K-split partials
// ---------------------------------------------------------------------------
__global__ void reduce12(const float* __restrict__ P2, float* __restrict__ out) {
    int idx = blockIdx.x * 256 + threadIdx.x;   // over 2048*512
    if (idx >= 2048 * 512) return;
    float s = 0.f;
#pragma unroll
    for (int sp = 0; sp < 12; ++sp)
        s += P2[(size_t)sp * 1048576 + idx];
    out[idx] = s;
}

// ---------------------------------------------------------------------------
// Launch
// ---------------------------------------------------------------------------
extern "C" void kernel_launch(void* const* d_in, const int* in_sizes, int n_in,
                              void* d_out, int out_size, void* d_ws, size_t ws_size,
                              hipStream_t stream) {
    const float* x   = (const float*)d_in[0];
    const float* phi = (const float*)d_in[1];
    const float* M   = (const float*)d_in[2];
    const float* Mp  = (const float*)d_in[3];
    const float* Mm  = (const float*)d_in[4];
    float* out = (float*)d_out;
    char* ws = (char*)d_ws;

    // workspace layout (bytes)
    bf16*  Tb = (bf16*)(ws + 0);           //  25,165,824
    bf16*  xT = (bf16*)(ws + 25165824);    //   2,097,152
    bf16*  A2 = (bf16*)(ws + 27262976);    // 106,954,752  [2048 x 26112]
    bf16*  B2 = (bf16*)(ws + 134217728);   //  26,738,688  [ 512 x 26112]
    float* P2 = (float*)(ws + 160956416);  //  50,331,648  [12 x 2048 x 512]
                                           //  total 211,288,064

    prep_all<<<6144, 256, 0, stream>>>(x, phi, M, Mp, Mm, xT, A2, B2, Tb);
    conv_gemm<<<3072, 256, 0, stream>>>(Tb, xT, A2);
    proj_gemm<<<dim3(16, 12, 4), 256, 0, stream>>>(A2, B2, P2);
    reduce12<<<4096, 256, 0, stream>>>(P2, out);
}